// Round 12
// baseline (215.946 us; speedup 1.0000x reference)
//
#include <hip/hip_runtime.h>
#include <hip/hip_bf16.h>

// Problem constants
#define B_   2
#define T_   2048
#define D_   1024
#define NH_  16
#define HD_  64
#define MROWS (B_*T_)              // 4096
#define HEADELEMS (B_*NH_*T_*HD_)  // 4194304 per Q/K/V tensor

// exp(s/8) = 2^(s * 0.125 * log2 e); folded into Q at the QKV epilogue
#define QSCALE 0.180336880f

typedef unsigned short u16;
typedef unsigned int   u32;

typedef float f32x4  __attribute__((ext_vector_type(4)));
typedef short bf16x8 __attribute__((ext_vector_type(8)));

// async global->LDS, 16 B/lane; LDS dest = wave-uniform base + lane*16
#define GLP(g, l) __builtin_amdgcn_global_load_lds(                         \
    (const __attribute__((address_space(1))) void*)(g),                     \
    (__attribute__((address_space(3))) void*)(l), 16, 0, 0)

struct Fc { static constexpr bool value = false; };
struct Tc { static constexpr bool value = true;  };

__device__ __forceinline__ u16 f2bf(float f) {
    u32 x = __float_as_uint(f);
    u32 r = (x + 0x7fffu + ((x >> 16) & 1u)) >> 16;
    return (u16)r;
}
// packed fp32x2 -> bf16x2
__device__ __forceinline__ u32 pkbf2(float a, float b) {
    __hip_bfloat162 h = __float22bfloat162_rn(make_float2(a, b));
    union { __hip_bfloat162 h2; u32 u; } cv; cv.h2 = h; return cv.u;
}

// ---------------------------------------------------------------------------
// Fused prep: [0,4096) x fp32->bf16; [4096,4864) Wqkv -> bf16 T;
// [4864,5120) Wproj -> bf16 T (only launched on the huge-ws path).
// ---------------------------------------------------------------------------
__device__ __forceinline__ void transpose_tile(const float* in, u16* out,
                                               int K, int N, int bx, int by,
                                               int t, float (*Ts)[65])
{
    const int n0 = bx * 64;
    const int k0 = by * 64;
    #pragma unroll
    for (int pass = 0; pass < 4; pass++) {
        const int r = pass * 16 + (t >> 4);
        const int c = (t & 15) * 4;
        float4 v = *(const float4*)(in + (size_t)(k0 + r) * N + n0 + c);
        Ts[r][c] = v.x; Ts[r][c+1] = v.y; Ts[r][c+2] = v.z; Ts[r][c+3] = v.w;
    }
    __syncthreads();
    #pragma unroll
    for (int pass = 0; pass < 2; pass++) {
        const int nn = pass * 32 + (t >> 3);
        const int kk = (t & 7) * 8;
        u16 o[8];
        #pragma unroll
        for (int j = 0; j < 8; j++) o[j] = f2bf(Ts[kk + j][nn]);
        *(uint4*)(out + (size_t)(n0 + nn) * K + k0 + kk) = *(const uint4*)o;
    }
}

__global__ __launch_bounds__(256)
void prep_kernel(const float* __restrict__ x, const float* __restrict__ Wqkv,
                 const float* __restrict__ Wproj, u16* __restrict__ xb,
                 u16* __restrict__ WqkvT, u16* __restrict__ WprojT)
{
    __shared__ float Ts[64][65];
    const int bid = blockIdx.x;
    const int t   = threadIdx.x;
    if (bid < 4096) {
        int i = bid * 256 + t;
        float4 v = ((const float4*)x)[i];
        ushort4 o;
        o.x = f2bf(v.x); o.y = f2bf(v.y); o.z = f2bf(v.z); o.w = f2bf(v.w);
        ((ushort4*)xb)[i] = o;
    } else if (bid < 4096 + 768) {
        int tb = bid - 4096;                   // [3072][1024] T
        transpose_tile(Wqkv, WqkvT, D_, 3*D_, tb % 48, tb / 48, t, Ts);
    } else {
        int tb = bid - 4864;                   // [1024][1024] T
        transpose_tile(Wproj, WprojT, D_, D_, tb % 16, tb / 16, t, Ts);
    }
}

__global__ __launch_bounds__(256)
void transpose_conv_kernel(const float* __restrict__ in, u16* __restrict__ out,
                           int K, int N)
{
    __shared__ float Ts[64][65];
    transpose_tile(in, out, K, N, blockIdx.x, blockIdx.y, threadIdx.x, Ts);
}

// ---------------------------------------------------------------------------
// MFMA GEMM (m97 structure): 128x128, BK=32, global_load_lds staging with
// global-side XOR segment swizzle.
// MODE 0: fp32 row-major + bias (normal acc orientation, scalar stores).
// MODE 1: QKV scatter. Round-12 epilogue rewrite (was 64 scalar u16
//   stores/thread -> 1.8x HBM write amplification, 62 us write-bound):
//   * Q/K (n0<2048): acc computed TRANSPOSED (swap mfma operand slots;
//     A/B frags share lane layout) -> C^T rows=n, cols=m. Then r10's
//     verified shuffle redistribution: lane l16 holds row tt, 8 consecutive
//     hd -> 8 uint4 (16B) stores/thread.
//   * V (n0>=2048): normal acc; regs are 4 consecutive tt -> pkbf2 pairs ->
//     16 uint2 (8B) stores/thread into V^T[hd][tt].
//   sec is block-uniform (n0 128-aligned, sections 1024-wide).
// ---------------------------------------------------------------------------
template <int MODE>
__global__ __launch_bounds__(256)
void gemm_mfma(const u16* __restrict__ A, const u16* __restrict__ BT,
               const float* __restrict__ bias, void* __restrict__ outv,
               int M, int N, int K)
{
    __shared__ u16 As[128][32];
    __shared__ u16 Bs[128][32];

    const int t    = threadIdx.x;
    const int wave = t >> 6;
    const int lane = t & 63;
    const int l16  = lane & 15;
    const int quad = lane >> 4;

    const int m0 = blockIdx.y * 128;
    const int n0 = blockIdx.x * 128;
    const int mb = (wave >> 1) * 64;
    const int nb = (wave & 1) * 64;

    const int r0a  = wave * 16;
    const int r0b  = 64 + wave * 16;
    const int lr_a = r0a + (lane >> 2);
    const int lr_b = r0b + (lane >> 2);
    const int sega = (((lane & 3) ^ ((lr_a >> 1) & 3))) * 8;
    const int segb = (((lane & 3) ^ ((lr_b >> 1) & 3))) * 8;

    const u16* gA0 = A  + (size_t)(m0 + lr_a) * K + sega;
    const u16* gA1 = A  + (size_t)(m0 + lr_b) * K + segb;
    const u16* gB0 = BT + (size_t)(n0 + lr_a) * K + sega;
    const u16* gB1 = BT + (size_t)(n0 + lr_b) * K + segb;

    const int fragoff = (quad ^ ((l16 >> 1) & 3)) * 8;

    // Q/K sections use transposed accumulation (see header)
    const bool swapT = (MODE == 1) && (n0 < 2*D_);

    f32x4 acc[4][4];
    #pragma unroll
    for (int i = 0; i < 4; i++)
        #pragma unroll
        for (int j = 0; j < 4; j++) acc[i][j] = (f32x4){0,0,0,0};

    for (int k0 = 0; k0 < K; k0 += 32) {
        __syncthreads();
        GLP(gA0 + k0, &As[r0a][0]);
        GLP(gA1 + k0, &As[r0b][0]);
        GLP(gB0 + k0, &Bs[r0a][0]);
        GLP(gB1 + k0, &Bs[r0b][0]);
        __syncthreads();

        bf16x8 af[4], bfr[4];
        #pragma unroll
        for (int i = 0; i < 4; i++)
            af[i] = *(const bf16x8*)&As[mb + i*16 + l16][fragoff];
        #pragma unroll
        for (int j = 0; j < 4; j++)
            bfr[j] = *(const bf16x8*)&Bs[nb + j*16 + l16][fragoff];

        if (swapT) {
            #pragma unroll
            for (int p = 0; p < 4; p++)          // p = n-frag
                #pragma unroll
                for (int q = 0; q < 4; q++)      // q = m-frag
                    acc[p][q] = __builtin_amdgcn_mfma_f32_16x16x32_bf16(
                        bfr[p], af[q], acc[p][q], 0, 0, 0);
        } else {
            #pragma unroll
            for (int p = 0; p < 4; p++)          // p = m-frag
                #pragma unroll
                for (int q = 0; q < 4; q++)      // q = n-frag
                    acc[p][q] = __builtin_amdgcn_mfma_f32_16x16x32_bf16(
                        af[p], bfr[q], acc[p][q], 0, 0, 0);
        }
    }

    const int nsec = n0 + nb;                    // 64-aligned

    if (MODE == 0) {
        // normal orientation: row m = mb+p*16+quad*4+r, col n = nsec+q*16+l16
        #pragma unroll
        for (int q = 0; q < 4; q++) {
            const int n = nsec + q*16 + l16;
            const float bv = bias[n];
            #pragma unroll
            for (int p = 0; p < 4; p++)
                #pragma unroll
                for (int r = 0; r < 4; r++) {
                    const int m = m0 + mb + p*16 + quad*4 + r;
                    ((float*)outv)[(size_t)m * N + n] = acc[p][q][r] + bv;
                }
        }
        return;
    }

    // MODE 1
    const int sec = nsec >> 10;                  // 0=q 1=k 2=v
    const int dd  = nsec & 1023;
    const int h   = dd >> 6;
    const int bb  = m0 >> 11;                    // batch (block m-range 128)
    const size_t hbase = ((size_t)(bb*NH_ + h)) * T_ * HD_;
    u16* out = (u16*)outv;

    if (sec == 2) {
        // V: normal acc; regs = 4 consecutive tt; store uint2 into VT[hd][tt]
        #pragma unroll
        for (int q = 0; q < 4; q++) {
            const int hd = (q*16 + l16) & 63;
            const float bv = bias[nsec + q*16 + l16];
            u16* rowp = out + (size_t)2 * HEADELEMS + hbase + (size_t)hd * T_;
            #pragma unroll
            for (int p = 0; p < 4; p++) {
                const int tt = (m0 + mb + p*16 + quad*4) & 2047;
                u32 w0 = pkbf2(acc[p][q][0] + bv, acc[p][q][1] + bv);
                u32 w1 = pkbf2(acc[p][q][2] + bv, acc[p][q][3] + bv);
                *(uint2*)(rowp + tt) = make_uint2(w0, w1);
            }
        }
    } else {
        // Q/K: transposed acc (rows=n, cols=m). Bias per C^T row (reg-indexed)
        // via float4 loads; then r10 shuffle redistribution -> lane holds
        // row tt = l16-based, 8 consecutive hd -> uint4 stores.
        const float sc = (sec == 0) ? QSCALE : 1.0f;
        float4 bv4[4];
        #pragma unroll
        for (int p = 0; p < 4; p++)
            bv4[p] = *(const float4*)(bias + nsec + p*16 + quad*4);

        const int srcA  = l16 + ((quad & 1) << 5);
        const int srcB  = srcA + 16;
        const bool selhi = (quad >> 1) != 0;

        const size_t sbase = (size_t)sec * HEADELEMS + hbase;

        #pragma unroll
        for (int q = 0; q < 4; q++) {            // q = m-frag
            u32 p01[4], p23[4];
            #pragma unroll
            for (int p = 0; p < 4; p++) {        // p = n-frag
                float v0 = (acc[p][q][0] + bv4[p].x) * sc;
                float v1 = (acc[p][q][1] + bv4[p].y) * sc;
                float v2 = (acc[p][q][2] + bv4[p].z) * sc;
                float v3 = (acc[p][q][3] + bv4[p].w) * sc;
                p01[p] = pkbf2(v0, v1);
                p23[p] = pkbf2(v2, v3);
            }
            const int tt = (m0 + mb + q*16 + l16) & 2047;
            u16* rowp = out + sbase + (size_t)tt * HD_;
            #pragma unroll
            for (int c = 0; c < 2; c++) {
                u32 t0, t1, r01, r23, r45, r67;
                t0 = (u32)__shfl((int)p01[2*c],   srcA);
                t1 = (u32)__shfl((int)p01[2*c+1], srcA);
                r01 = selhi ? t1 : t0;
                t0 = (u32)__shfl((int)p23[2*c],   srcA);
                t1 = (u32)__shfl((int)p23[2*c+1], srcA);
                r23 = selhi ? t1 : t0;
                t0 = (u32)__shfl((int)p01[2*c],   srcB);
                t1 = (u32)__shfl((int)p01[2*c+1], srcB);
                r45 = selhi ? t1 : t0;
                t0 = (u32)__shfl((int)p23[2*c],   srcB);
                t1 = (u32)__shfl((int)p23[2*c+1], srcB);
                r67 = selhi ? t1 : t0;
                *(uint4*)(rowp + 32*c + quad*8) = make_uint4(r01, r23, r45, r67);
            }
        }
    }
}

// ---------------------------------------------------------------------------
// MFMA flash attention v6 (unchanged from r11): 64 q-rows/block, grid
// (hb=32, y=32) = 1024 blocks -> 4 blocks/CU; in-register C->A shuffle;
// ones-MFMA row sums; compile-time masked-tile split; XCD-pinned heads.
// ---------------------------------------------------------------------------
__global__ __launch_bounds__(256)
void attn_mfma_kernel(const u16* __restrict__ Q, const u16* __restrict__ K,
                      const u16* __restrict__ VT, u16* __restrict__ y1)
{
    __shared__ u16 Ks[2][64][72];     // [buf][key][d]
    __shared__ u16 Vs[2][64][72];     // [buf][d][key]

    const int t    = threadIdx.x;
    const int wave = t >> 6;
    const int lane = t & 63;
    const int l16  = lane & 15;
    const int quad = lane >> 4;

    const int hb = blockIdx.x;                 // b*NH + h (XCD-pinned)
    const int yy = blockIdx.y;
    const int a  = yy & 7, g = yy >> 3;
    const int qt = (g == 0) ? 31 - a : (g == 1) ? 16 + a
                 : (g == 2) ? 15 - a : a;      // balanced 4-way pairing
    const int b  = hb >> 4;
    const int h  = hb & 15;
    const size_t base = (size_t)hb * T_ * HD_;

    const int qw0 = qt * 64 + wave * 16;       // first q-row of this wave

    bf16x8 qf[2];
    {
        const u16* qp = Q + base + (size_t)(qw0 + l16) * HD_ + quad * 8;
        qf[0] = *(const bf16x8*)(qp);
        qf[1] = *(const bf16x8*)(qp + 32);
    }

    bf16x8 onesf;
    #pragma unroll
    for (int i = 0; i < 8; i++) onesf[i] = (short)0x3F80;

    f32x4 o[4];
    #pragma unroll
    for (int d = 0; d < 4; d++) o[d] = (f32x4){0,0,0,0};
    f32x4 accl = (f32x4){0,0,0,0};

    const int nsteps = qt + 1;

    const int srow = t >> 3;
    const int scol = (t & 7) * 8;

    const int srcA  = l16 + ((quad & 1) << 5);
    const int srcB  = srcA + 16;
    const bool selhi = (quad >> 1) != 0;

    uint4 kr0, kr1, vr0, vr1;
    {
        const u16* kp = K + base + (size_t)srow * HD_ + scol;
        kr0 = *(const uint4*)kp;
        kr1 = *(const uint4*)(kp + 32 * HD_);
        const u16* vp = VT + base + (size_t)srow * T_ + scol;
        vr0 = *(const uint4*)vp;
        vr1 = *(const uint4*)(vp + 32 * T_);
        *(uint4*)&Ks[0][srow][scol]      = kr0;
        *(uint4*)&Ks[0][srow + 32][scol] = kr1;
        *(uint4*)&Vs[0][srow][scol]      = vr0;
        *(uint4*)&Vs[0][srow + 32][scol] = vr1;
    }
    __syncthreads();

    auto compute_tile = [&](int cur, int k0, auto mc) {
        constexpr bool MASKED = decltype(mc)::value;
        f32x4 st[4];
        #pragma unroll
        for (int j = 0; j < 4; j++) {
            bf16x8 kf0 = *(const bf16x8*)&Ks[cur][j*16 + l16][quad * 8];
            bf16x8 kf1 = *(const bf16x8*)&Ks[cur][j*16 + l16][32 + quad * 8];
            f32x4 z = {0,0,0,0};
            z = __builtin_amdgcn_mfma_f32_16x16x32_bf16(kf0, qf[0], z, 0, 0, 0);
            st[j] = __builtin_amdgcn_mfma_f32_16x16x32_bf16(kf1, qf[1], z, 0, 0, 0);
        }

        u32 p01[4], p23[4];
        const int qi = qw0 + l16;
        #pragma unroll
        for (int j = 0; j < 4; j++) {
            const int kb = k0 + j*16 + quad*4;
            float e0 = __builtin_amdgcn_exp2f(st[j][0]);
            float e1 = __builtin_amdgcn_exp2f(st[j][1]);
            float e2 = __builtin_amdgcn_exp2f(st[j][2]);
            float e3 = __builtin_amdgcn_exp2f(st[j][3]);
            if (MASKED) {
                if (kb + 0 > qi) e0 = 0.f;
                if (kb + 1 > qi) e1 = 0.f;
                if (kb + 2 > qi) e2 = 0.f;
                if (kb + 3 > qi) e3 = 0.f;
            }
            p01[j] = pkbf2(e0, e1);
            p23[j] = pkbf2(e2, e3);
        }

        bf16x8 pf[2];
        #pragma unroll
        for (int c = 0; c < 2; c++) {
            u32 t0, t1, r01, r23, r45, r67;
            t0 = (u32)__shfl((int)p01[2*c],   srcA);
            t1 = (u32)__shfl((int)p01[2*c+1], srcA);
            r01 = selhi ? t1 : t0;
            t0 = (u32)__shfl((int)p23[2*c],   srcA);
            t1 = (u32)__shfl((int)p23[2*c+1], srcA);
            r23 = selhi ? t1 : t0;
            t0 = (u32)__shfl((int)p01[2*c],   srcB);
            t1 = (u32)__shfl((int)p01[2*c+1], srcB);
            r45 = selhi ? t1 : t0;
            t0 = (u32)__shfl((int)p23[2*c],   srcB);
            t1 = (u32)__shfl((int)p23[2*c+1], srcB);
            r67 = selhi ? t1 : t0;
            union { u32 u[4]; bf16x8 v; } pk;
            pk.u[0] = r01; pk.u[1] = r23; pk.u[2] = r45; pk.u[3] = r67;
            pf[c] = pk.v;
        }
        accl = __builtin_amdgcn_mfma_f32_16x16x32_bf16(pf[0], onesf, accl, 0, 0, 0);
        accl = __builtin_amdgcn_mfma_f32_16x16x32_bf16(pf[1], onesf, accl, 0, 0, 0);
        #pragma unroll
        for (int d = 0; d < 4; d++) {
            bf16x8 v0 = *(const bf16x8*)&Vs[cur][d*16 + l16][quad * 8];
            bf16x8 v1 = *(const bf16x8*)&Vs[cur][d*16 + l16][32 + quad * 8];
            o[d] = __builtin_amdgcn_mfma_f32_16x16x32_bf16(pf[0], v0, o[d], 0, 0, 0);
            o[d] = __builtin_amdgcn_mfma_f32_16x16x32_bf16(pf[1], v1, o[d], 0, 0, 0);
        }
    };

    for (int kt = 0; kt < nsteps; kt++) {
        const int cur = kt & 1;
        const int k0  = kt * 64;
        const bool have_next = (kt + 1 < nsteps);

        if (have_next) {
            const u16* kp = K + base + (size_t)(k0 + 64 + srow) * HD_ + scol;
            kr0 = *(const uint4*)kp;
            kr1 = *(const uint4*)(kp + 32 * HD_);
            const u16* vp = VT + base + (size_t)srow * T_ + k0 + 64 + scol;
            vr0 = *(const uint4*)vp;
            vr1 = *(const uint4*)(vp + 32 * T_);
        }

        if (kt < qt) compute_tile(cur, k0, Fc{});
        else         compute_tile(cur, k0, Tc{});

        if (have_next) {
            const int nxt = cur ^ 1;
            *(uint4*)&Ks[nxt][srow][scol]      = kr0;
            *(uint4*)&Ks[nxt][srow + 32][scol] = kr1;
            *(uint4*)&Vs[nxt][srow][scol]      = vr0;
            *(uint4*)&Vs[nxt][srow + 32][scol] = vr1;
            __syncthreads();
        }
    }

    #pragma unroll
    for (int r = 0; r < 4; r++) {
        const float inv = 1.f / accl[r];
        const int qi = qw0 + quad*4 + r;
        u16* yp = y1 + ((size_t)(b * T_ + qi)) * D_ + h * HD_ + l16;
        yp[0]  = f2bf(o[0][r] * inv);
        yp[16] = f2bf(o[1][r] * inv);
        yp[32] = f2bf(o[2][r] * inv);
        yp[48] = f2bf(o[3][r] * inv);
    }
}

// ---------------------------------------------------------------------------
// Choreography, three ws tiers (unchanged from r11):
//  huge: prep also transposes Wproj into ws; attn -> y1 in ws; no memcpy.
//  big : y1 in ws; WprojT over dead K after attn.
//  small: y1 over dead xb in d_out; memcpy to dead VT; WprojT over dead K.
// ---------------------------------------------------------------------------
extern "C" void kernel_launch(void* const* d_in, const int* in_sizes, int n_in,
                              void* d_out, int out_size, void* d_ws, size_t ws_size,
                              hipStream_t stream)
{
    const float* x     = (const float*)d_in[0];
    const float* Wqkv  = (const float*)d_in[1];
    const float* bqkv  = (const float*)d_in[2];
    const float* Wproj = (const float*)d_in[3];
    const float* bproj = (const float*)d_in[4];

    u16* scratch = (u16*)d_out;
    u16* xb      = scratch;
    u16* WqkvT   = scratch + (size_t)MROWS * D_;

    const size_t Y1E = (size_t)MROWS * D_;
    const size_t WPE = (size_t)D_ * D_;

    u16* qkv = (u16*)d_ws;
    u16* Qp  = qkv;
    u16* Kp  = qkv + (size_t)HEADELEMS;
    u16* Vtp = qkv + (size_t)2 * HEADELEMS;

    const bool huge = ws_size >= ((size_t)3 * HEADELEMS + Y1E + WPE) * 2;
    const bool big  = ws_size >= ((size_t)3 * HEADELEMS + Y1E) * 2;

    u16* y1b    = big ? qkv + (size_t)3 * HEADELEMS : scratch;
    u16* y1g    = big ? y1b : Vtp;
    u16* WprojT = huge ? qkv + (size_t)3 * HEADELEMS + Y1E : Kp;

    // 1) fused prep
    prep_kernel<<<huge ? 5120 : 4864, 256, 0, stream>>>(
        x, Wqkv, Wproj, xb, WqkvT, WprojT);

    // 2) QKV GEMM -> Q(prescaled) | K | VT (bf16) in ws
    gemm_mfma<1><<<dim3(3*D_/128, MROWS/128), 256, 0, stream>>>(
        xb, WqkvT, bqkv, (void*)qkv, MROWS, 3*D_, D_);

    // 3) attention -> y1 bf16
    attn_mfma_kernel<<<dim3(NH_*B_, T_/64), 256, 0, stream>>>(Qp, Kp, Vtp, y1b);

    // 4) Wproj transpose (non-huge paths; K dead now)
    if (!huge)
        transpose_conv_kernel<<<dim3(D_/64, D_/64), 256, 0, stream>>>(
            Wproj, WprojT, D_, D_);

    // 5) small-ws fallback: move y1 out of d_out
    if (!big)
        (void)hipMemcpyAsync(y1g, y1b, Y1E * sizeof(u16),
                             hipMemcpyDeviceToDevice, stream);

    // 6) output projection -> fp32 d_out
    gemm_mfma<0><<<dim3(D_/128, MROWS/128), 256, 0, stream>>>(
        y1g, WprojT, bproj, d_out, MROWS, D_, D_);
}

// Round 13
// 200.672 us; speedup vs baseline: 1.0761x; 1.0761x over previous
//
#include <hip/hip_runtime.h>
#include <hip/hip_bf16.h>

// Problem constants
#define B_   2
#define T_   2048
#define D_   1024
#define NH_  16
#define HD_  64
#define MROWS (B_*T_)              // 4096
#define HEADELEMS (B_*NH_*T_*HD_)  // 4194304 per Q/K/V tensor

// exp(s/8) = 2^(s * 0.125 * log2 e); folded into Q at the QKV epilogue
#define QSCALE 0.180336880f

typedef unsigned short u16;
typedef unsigned int   u32;

typedef float f32x4  __attribute__((ext_vector_type(4)));
typedef short bf16x8 __attribute__((ext_vector_type(8)));

// async global->LDS, 16 B/lane; LDS dest = wave-uniform base + lane*16
#define GLP(g, l) __builtin_amdgcn_global_load_lds(                         \
    (const __attribute__((address_space(1))) void*)(g),                     \
    (__attribute__((address_space(3))) void*)(l), 16, 0, 0)

struct Fc { static constexpr bool value = false; };
struct Tc { static constexpr bool value = true;  };

__device__ __forceinline__ u16 f2bf(float f) {
    u32 x = __float_as_uint(f);
    u32 r = (x + 0x7fffu + ((x >> 16) & 1u)) >> 16;
    return (u16)r;
}
// packed fp32x2 -> bf16x2
__device__ __forceinline__ u32 pkbf2(float a, float b) {
    __hip_bfloat162 h = __float22bfloat162_rn(make_float2(a, b));
    union { __hip_bfloat162 h2; u32 u; } cv; cv.h2 = h; return cv.u;
}

// ---------------------------------------------------------------------------
// Fused prep: [0,4096) x fp32->bf16; [4096,4864) Wqkv -> bf16 T;
// [4864,5120) Wproj -> bf16 T (only launched on the huge-ws path).
// ---------------------------------------------------------------------------
__device__ __forceinline__ void transpose_tile(const float* in, u16* out,
                                               int K, int N, int bx, int by,
                                               int t, float (*Ts)[65])
{
    const int n0 = bx * 64;
    const int k0 = by * 64;
    #pragma unroll
    for (int pass = 0; pass < 4; pass++) {
        const int r = pass * 16 + (t >> 4);
        const int c = (t & 15) * 4;
        float4 v = *(const float4*)(in + (size_t)(k0 + r) * N + n0 + c);
        Ts[r][c] = v.x; Ts[r][c+1] = v.y; Ts[r][c+2] = v.z; Ts[r][c+3] = v.w;
    }
    __syncthreads();
    #pragma unroll
    for (int pass = 0; pass < 2; pass++) {
        const int nn = pass * 32 + (t >> 3);
        const int kk = (t & 7) * 8;
        u16 o[8];
        #pragma unroll
        for (int j = 0; j < 8; j++) o[j] = f2bf(Ts[kk + j][nn]);
        *(uint4*)(out + (size_t)(n0 + nn) * K + k0 + kk) = *(const uint4*)o;
    }
}

__global__ __launch_bounds__(256)
void prep_kernel(const float* __restrict__ x, const float* __restrict__ Wqkv,
                 const float* __restrict__ Wproj, u16* __restrict__ xb,
                 u16* __restrict__ WqkvT, u16* __restrict__ WprojT)
{
    __shared__ float Ts[64][65];
    const int bid = blockIdx.x;
    const int t   = threadIdx.x;
    if (bid < 4096) {
        int i = bid * 256 + t;
        float4 v = ((const float4*)x)[i];
        ushort4 o;
        o.x = f2bf(v.x); o.y = f2bf(v.y); o.z = f2bf(v.z); o.w = f2bf(v.w);
        ((ushort4*)xb)[i] = o;
    } else if (bid < 4096 + 768) {
        int tb = bid - 4096;                   // [3072][1024] T
        transpose_tile(Wqkv, WqkvT, D_, 3*D_, tb % 48, tb / 48, t, Ts);
    } else {
        int tb = bid - 4864;                   // [1024][1024] T
        transpose_tile(Wproj, WprojT, D_, D_, tb % 16, tb / 16, t, Ts);
    }
}

__global__ __launch_bounds__(256)
void transpose_conv_kernel(const float* __restrict__ in, u16* __restrict__ out,
                           int K, int N)
{
    __shared__ float Ts[64][65];
    transpose_tile(in, out, K, N, blockIdx.x, blockIdx.y, threadIdx.x, Ts);
}

// ---------------------------------------------------------------------------
// MFMA GEMM (m97 structure), round-13: compile-time specialization.
//   MODE 0: fp32 row-major + bias (proj).          [acc normal, MF m-frags]
//   MODE 1: Q/K scatter, acc TRANSPOSED (swap mfma operand slots) + r10
//           shuffle redistribution -> uint4 stores. [MF=4 only]
//   MODE 2: V scatter -> V^T[hd][tt], acc normal -> uint2 stores.
// MF = m-frags per wave (tile = MF*32 x 128). MF=2 halves the tile for
// more blocks (latency hiding on short K loops); MF=4 = classic 128x128.
// No runtime branch in the main loop (r12's 16-VGPR/occupancy regression).
// ---------------------------------------------------------------------------
template <int MODE, int MF>
__global__ __launch_bounds__(256)
void gemm_mfma(const u16* __restrict__ A, const u16* __restrict__ BT,
               const float* __restrict__ bias, void* __restrict__ outv,
               int M, int N, int K, int n0base)
{
    constexpr int MTILE = MF * 32;
    __shared__ u16 As[MTILE][32];
    __shared__ u16 Bs[128][32];

    const int t    = threadIdx.x;
    const int wave = t >> 6;
    const int lane = t & 63;
    const int l16  = lane & 15;
    const int quad = lane >> 4;

    const int m0 = blockIdx.y * MTILE;
    const int n0 = n0base + blockIdx.x * 128;
    const int mb = (wave >> 1) * (MF * 16);
    const int nb = (wave & 1) * 64;

    // staging rows: each GLP covers 16 rows (64 lanes x 16B = 1KB)
    const int r0a  = wave * 16;            // A rows [w*16,+16) (+64 if MF=4)
    const int r0b  = 64 + wave * 16;
    const int lr_a = r0a + (lane >> 2);
    const int lr_b = r0b + (lane >> 2);
    const int sega = (((lane & 3) ^ ((lr_a >> 1) & 3))) * 8;
    const int segb = (((lane & 3) ^ ((lr_b >> 1) & 3))) * 8;

    const u16* gA0 = A  + (size_t)(m0 + lr_a) * K + sega;
    const u16* gA1 = A  + (size_t)(m0 + lr_b) * K + segb;   // MF=4 only
    const u16* gB0 = BT + (size_t)(n0 + lr_a) * K + sega;
    const u16* gB1 = BT + (size_t)(n0 + lr_b) * K + segb;

    const int fragoff = (quad ^ ((l16 >> 1) & 3)) * 8;

    f32x4 acc[4][4];
    #pragma unroll
    for (int i = 0; i < 4; i++)
        #pragma unroll
        for (int j = 0; j < 4; j++) acc[i][j] = (f32x4){0,0,0,0};

    for (int k0 = 0; k0 < K; k0 += 32) {
        __syncthreads();
        GLP(gA0 + k0, &As[r0a][0]);
        if constexpr (MF == 4) GLP(gA1 + k0, &As[r0b][0]);
        GLP(gB0 + k0, &Bs[r0a][0]);
        GLP(gB1 + k0, &Bs[r0b][0]);
        __syncthreads();

        bf16x8 af[MF], bfr[4];
        #pragma unroll
        for (int i = 0; i < MF; i++)
            af[i] = *(const bf16x8*)&As[mb + i*16 + l16][fragoff];
        #pragma unroll
        for (int j = 0; j < 4; j++)
            bfr[j] = *(const bf16x8*)&Bs[nb + j*16 + l16][fragoff];

        if constexpr (MODE == 1) {
            #pragma unroll
            for (int p = 0; p < 4; p++)          // p = n-frag
                #pragma unroll
                for (int q = 0; q < MF; q++)     // q = m-frag
                    acc[p][q] = __builtin_amdgcn_mfma_f32_16x16x32_bf16(
                        bfr[p], af[q], acc[p][q], 0, 0, 0);
        } else {
            #pragma unroll
            for (int p = 0; p < MF; p++)         // p = m-frag
                #pragma unroll
                for (int q = 0; q < 4; q++)      // q = n-frag
                    acc[p][q] = __builtin_amdgcn_mfma_f32_16x16x32_bf16(
                        af[p], bfr[q], acc[p][q], 0, 0, 0);
        }
    }

    const int nsec = n0 + nb;                    // 64-aligned

    if constexpr (MODE == 0) {
        #pragma unroll
        for (int q = 0; q < 4; q++) {
            const int n = nsec + q*16 + l16;
            const float bv = bias[n];
            #pragma unroll
            for (int p = 0; p < MF; p++)
                #pragma unroll
                for (int r = 0; r < 4; r++) {
                    const int m = m0 + mb + p*16 + quad*4 + r;
                    ((float*)outv)[(size_t)m * N + n] = acc[p][q][r] + bv;
                }
        }
        return;
    }

    const int dd  = nsec & 1023;
    const int h   = dd >> 6;
    const int bb  = m0 >> 11;
    const size_t hbase = ((size_t)(bb*NH_ + h)) * T_ * HD_;
    u16* out = (u16*)outv;

    if constexpr (MODE == 2) {
        // V: normal acc; regs = 4 consecutive tt -> uint2 into VT[hd][tt]
        #pragma unroll
        for (int q = 0; q < 4; q++) {
            const int hd = (q*16 + l16) & 63;
            const float bv = bias[nsec + q*16 + l16];
            u16* rowp = out + (size_t)2 * HEADELEMS + hbase + (size_t)hd * T_;
            #pragma unroll
            for (int p = 0; p < MF; p++) {
                const int tt = (m0 + mb + p*16 + quad*4) & 2047;
                u32 w0 = pkbf2(acc[p][q][0] + bv, acc[p][q][1] + bv);
                u32 w1 = pkbf2(acc[p][q][2] + bv, acc[p][q][3] + bv);
                *(uint2*)(rowp + tt) = make_uint2(w0, w1);
            }
        }
    }

    if constexpr (MODE == 1) {
        // Q/K: transposed acc; r10 shuffle redistribution -> uint4 stores
        const int sec = nsec >> 10;              // 0=q 1=k
        const float sc = (sec == 0) ? QSCALE : 1.0f;
        float4 bv4[4];
        #pragma unroll
        for (int p = 0; p < 4; p++)
            bv4[p] = *(const float4*)(bias + nsec + p*16 + quad*4);

        const int srcA  = l16 + ((quad & 1) << 5);
        const int srcB  = srcA + 16;
        const bool selhi = (quad >> 1) != 0;

        const size_t sbase = (size_t)sec * HEADELEMS + hbase;

        #pragma unroll
        for (int q = 0; q < MF; q++) {           // q = m-frag
            u32 p01[4], p23[4];
            #pragma unroll
            for (int p = 0; p < 4; p++) {        // p = n-frag
                float v0 = (acc[p][q][0] + bv4[p].x) * sc;
                float v1 = (acc[p][q][1] + bv4[p].y) * sc;
                float v2 = (acc[p][q][2] + bv4[p].z) * sc;
                float v3 = (acc[p][q][3] + bv4[p].w) * sc;
                p01[p] = pkbf2(v0, v1);
                p23[p] = pkbf2(v2, v3);
            }
            const int tt = (m0 + mb + q*16 + l16) & 2047;
            u16* rowp = out + sbase + (size_t)tt * HD_;
            #pragma unroll
            for (int c = 0; c < 2; c++) {
                u32 t0, t1, r01, r23, r45, r67;
                t0 = (u32)__shfl((int)p01[2*c],   srcA);
                t1 = (u32)__shfl((int)p01[2*c+1], srcA);
                r01 = selhi ? t1 : t0;
                t0 = (u32)__shfl((int)p23[2*c],   srcA);
                t1 = (u32)__shfl((int)p23[2*c+1], srcA);
                r23 = selhi ? t1 : t0;
                t0 = (u32)__shfl((int)p01[2*c],   srcB);
                t1 = (u32)__shfl((int)p01[2*c+1], srcB);
                r45 = selhi ? t1 : t0;
                t0 = (u32)__shfl((int)p23[2*c],   srcB);
                t1 = (u32)__shfl((int)p23[2*c+1], srcB);
                r67 = selhi ? t1 : t0;
                *(uint4*)(rowp + 32*c + quad*8) = make_uint4(r01, r23, r45, r67);
            }
        }
    }
}

// ---------------------------------------------------------------------------
// MFMA flash attention v6 (unchanged from r11): 64 q-rows/block, grid
// (hb=32, y=32) = 1024 blocks -> 4 blocks/CU; in-register C->A shuffle;
// ones-MFMA row sums; compile-time masked-tile split; XCD-pinned heads.
// ---------------------------------------------------------------------------
__global__ __launch_bounds__(256)
void attn_mfma_kernel(const u16* __restrict__ Q, const u16* __restrict__ K,
                      const u16* __restrict__ VT, u16* __restrict__ y1)
{
    __shared__ u16 Ks[2][64][72];
    __shared__ u16 Vs[2][64][72];

    const int t    = threadIdx.x;
    const int wave = t >> 6;
    const int lane = t & 63;
    const int l16  = lane & 15;
    const int quad = lane >> 4;

    const int hb = blockIdx.x;
    const int yy = blockIdx.y;
    const int a  = yy & 7, g = yy >> 3;
    const int qt = (g == 0) ? 31 - a : (g == 1) ? 16 + a
                 : (g == 2) ? 15 - a : a;
    const int b  = hb >> 4;
    const int h  = hb & 15;
    const size_t base = (size_t)hb * T_ * HD_;

    const int qw0 = qt * 64 + wave * 16;

    bf16x8 qf[2];
    {
        const u16* qp = Q + base + (size_t)(qw0 + l16) * HD_ + quad * 8;
        qf[0] = *(const bf16x8*)(qp);
        qf[1] = *(const bf16x8*)(qp + 32);
    }

    bf16x8 onesf;
    #pragma unroll
    for (int i = 0; i < 8; i++) onesf[i] = (short)0x3F80;

    f32x4 o[4];
    #pragma unroll
    for (int d = 0; d < 4; d++) o[d] = (f32x4){0,0,0,0};
    f32x4 accl = (f32x4){0,0,0,0};

    const int nsteps = qt + 1;

    const int srow = t >> 3;
    const int scol = (t & 7) * 8;

    const int srcA  = l16 + ((quad & 1) << 5);
    const int srcB  = srcA + 16;
    const bool selhi = (quad >> 1) != 0;

    uint4 kr0, kr1, vr0, vr1;
    {
        const u16* kp = K + base + (size_t)srow * HD_ + scol;
        kr0 = *(const uint4*)kp;
        kr1 = *(const uint4*)(kp + 32 * HD_);
        const u16* vp = VT + base + (size_t)srow * T_ + scol;
        vr0 = *(const uint4*)vp;
        vr1 = *(const uint4*)(vp + 32 * T_);
        *(uint4*)&Ks[0][srow][scol]      = kr0;
        *(uint4*)&Ks[0][srow + 32][scol] = kr1;
        *(uint4*)&Vs[0][srow][scol]      = vr0;
        *(uint4*)&Vs[0][srow + 32][scol] = vr1;
    }
    __syncthreads();

    auto compute_tile = [&](int cur, int k0, auto mc) {
        constexpr bool MASKED = decltype(mc)::value;
        f32x4 st[4];
        #pragma unroll
        for (int j = 0; j < 4; j++) {
            bf16x8 kf0 = *(const bf16x8*)&Ks[cur][j*16 + l16][quad * 8];
            bf16x8 kf1 = *(const bf16x8*)&Ks[cur][j*16 + l16][32 + quad * 8];
            f32x4 z = {0,0,0,0};
            z = __builtin_amdgcn_mfma_f32_16x16x32_bf16(kf0, qf[0], z, 0, 0, 0);
            st[j] = __builtin_amdgcn_mfma_f32_16x16x32_bf16(kf1, qf[1], z, 0, 0, 0);
        }

        u32 p01[4], p23[4];
        const int qi = qw0 + l16;
        #pragma unroll
        for (int j = 0; j < 4; j++) {
            const int kb = k0 + j*16 + quad*4;
            float e0 = __builtin_amdgcn_exp2f(st[j][0]);
            float e1 = __builtin_amdgcn_exp2f(st[j][1]);
            float e2 = __builtin_amdgcn_exp2f(st[j][2]);
            float e3 = __builtin_amdgcn_exp2f(st[j][3]);
            if (MASKED) {
                if (kb + 0 > qi) e0 = 0.f;
                if (kb + 1 > qi) e1 = 0.f;
                if (kb + 2 > qi) e2 = 0.f;
                if (kb + 3 > qi) e3 = 0.f;
            }
            p01[j] = pkbf2(e0, e1);
            p23[j] = pkbf2(e2, e3);
        }

        bf16x8 pf[2];
        #pragma unroll
        for (int c = 0; c < 2; c++) {
            u32 t0, t1, r01, r23, r45, r67;
            t0 = (u32)__shfl((int)p01[2*c],   srcA);
            t1 = (u32)__shfl((int)p01[2*c+1], srcA);
            r01 = selhi ? t1 : t0;
            t0 = (u32)__shfl((int)p23[2*c],   srcA);
            t1 = (u32)__shfl((int)p23[2*c+1], srcA);
            r23 = selhi ? t1 : t0;
            t0 = (u32)__shfl((int)p01[2*c],   srcB);
            t1 = (u32)__shfl((int)p01[2*c+1], srcB);
            r45 = selhi ? t1 : t0;
            t0 = (u32)__shfl((int)p23[2*c],   srcB);
            t1 = (u32)__shfl((int)p23[2*c+1], srcB);
            r67 = selhi ? t1 : t0;
            union { u32 u[4]; bf16x8 v; } pk;
            pk.u[0] = r01; pk.u[1] = r23; pk.u[2] = r45; pk.u[3] = r67;
            pf[c] = pk.v;
        }
        accl = __builtin_amdgcn_mfma_f32_16x16x32_bf16(pf[0], onesf, accl, 0, 0, 0);
        accl = __builtin_amdgcn_mfma_f32_16x16x32_bf16(pf[1], onesf, accl, 0, 0, 0);
        #pragma unroll
        for (int d = 0; d < 4; d++) {
            bf16x8 v0 = *(const bf16x8*)&Vs[cur][d*16 + l16][quad * 8];
            bf16x8 v1 = *(const bf16x8*)&Vs[cur][d*16 + l16][32 + quad * 8];
            o[d] = __builtin_amdgcn_mfma_f32_16x16x32_bf16(pf[0], v0, o[d], 0, 0, 0);
            o[d] = __builtin_amdgcn_mfma_f32_16x16x32_bf16(pf[1], v1, o[d], 0, 0, 0);
        }
    };

    for (int kt = 0; kt < nsteps; kt++) {
        const int cur = kt & 1;
        const int k0  = kt * 64;
        const bool have_next = (kt + 1 < nsteps);

        if (have_next) {
            const u16* kp = K + base + (size_t)(k0 + 64 + srow) * HD_ + scol;
            kr0 = *(const uint4*)kp;
            kr1 = *(const uint4*)(kp + 32 * HD_);
            const u16* vp = VT + base + (size_t)srow * T_ + k0 + 64 + scol;
            vr0 = *(const uint4*)vp;
            vr1 = *(const uint4*)(vp + 32 * T_);
        }

        if (kt < qt) compute_tile(cur, k0, Fc{});
        else         compute_tile(cur, k0, Tc{});

        if (have_next) {
            const int nxt = cur ^ 1;
            *(uint4*)&Ks[nxt][srow][scol]      = kr0;
            *(uint4*)&Ks[nxt][srow + 32][scol] = kr1;
            *(uint4*)&Vs[nxt][srow][scol]      = vr0;
            *(uint4*)&Vs[nxt][srow + 32][scol] = vr1;
            __syncthreads();
        }
    }

    #pragma unroll
    for (int r = 0; r < 4; r++) {
        const float inv = 1.f / accl[r];
        const int qi = qw0 + quad*4 + r;
        u16* yp = y1 + ((size_t)(b * T_ + qi)) * D_ + h * HD_ + l16;
        yp[0]  = f2bf(o[0][r] * inv);
        yp[16] = f2bf(o[1][r] * inv);
        yp[32] = f2bf(o[2][r] * inv);
        yp[48] = f2bf(o[3][r] * inv);
    }
}

// ---------------------------------------------------------------------------
// Choreography, three ws tiers (as r11/r12); QKV GEMM now split into the
// Q/K launch (MODE 1, 128x128, 512 blocks) and V launch (MODE 2, 64x128,
// 512 blocks); proj uses 64x128 (512 blocks) for latency hiding.
// ---------------------------------------------------------------------------
extern "C" void kernel_launch(void* const* d_in, const int* in_sizes, int n_in,
                              void* d_out, int out_size, void* d_ws, size_t ws_size,
                              hipStream_t stream)
{
    const float* x     = (const float*)d_in[0];
    const float* Wqkv  = (const float*)d_in[1];
    const float* bqkv  = (const float*)d_in[2];
    const float* Wproj = (const float*)d_in[3];
    const float* bproj = (const float*)d_in[4];

    u16* scratch = (u16*)d_out;
    u16* xb      = scratch;
    u16* WqkvT   = scratch + (size_t)MROWS * D_;

    const size_t Y1E = (size_t)MROWS * D_;
    const size_t WPE = (size_t)D_ * D_;

    u16* qkv = (u16*)d_ws;
    u16* Qp  = qkv;
    u16* Kp  = qkv + (size_t)HEADELEMS;
    u16* Vtp = qkv + (size_t)2 * HEADELEMS;

    const bool huge = ws_size >= ((size_t)3 * HEADELEMS + Y1E + WPE) * 2;
    const bool big  = ws_size >= ((size_t)3 * HEADELEMS + Y1E) * 2;

    u16* y1b    = big ? qkv + (size_t)3 * HEADELEMS : scratch;
    u16* y1g    = big ? y1b : Vtp;
    u16* WprojT = huge ? qkv + (size_t)3 * HEADELEMS + Y1E : Kp;

    // 1) fused prep
    prep_kernel<<<huge ? 5120 : 4864, 256, 0, stream>>>(
        x, Wqkv, Wproj, xb, WqkvT, WprojT);

    // 2a) Q/K GEMM (transposed acc, coalesced scatter), n in [0,2048)
    gemm_mfma<1,4><<<dim3(16, MROWS/128), 256, 0, stream>>>(
        xb, WqkvT, bqkv, (void*)qkv, MROWS, 3*D_, D_, 0);

    // 2b) V GEMM (normal acc -> V^T), n in [2048,3072), 64-tall tiles
    gemm_mfma<2,2><<<dim3(8, MROWS/64), 256, 0, stream>>>(
        xb, WqkvT, bqkv, (void*)qkv, MROWS, 3*D_, D_, 2*D_);

    // 3) attention -> y1 bf16
    attn_mfma_kernel<<<dim3(NH_*B_, T_/64), 256, 0, stream>>>(Qp, Kp, Vtp, y1b);

    // 4) Wproj transpose (non-huge paths; K dead now)
    if (!huge)
        transpose_conv_kernel<<<dim3(D_/64, D_/64), 256, 0, stream>>>(
            Wproj, WprojT, D_, D_);

    // 5) small-ws fallback: move y1 out of d_out
    if (!big)
        (void)hipMemcpyAsync(y1g, y1b, Y1E * sizeof(u16),
                             hipMemcpyDeviceToDevice, stream);

    // 6) output projection -> fp32 d_out, 64-tall tiles (512 blocks)
    gemm_mfma<0,2><<<dim3(8, MROWS/64), 256, 0, stream>>>(
        y1g, WprojT, bproj, d_out, MROWS, D_, D_, 0);
}